// Round 3
// baseline (624.963 us; speedup 1.0000x reference)
//
#include <hip/hip_runtime.h>
#include <hip/hip_bf16.h>

typedef unsigned short ushort_t;
typedef __attribute__((ext_vector_type(8))) short short8;
typedef __attribute__((ext_vector_type(4))) float floatx4;

#define B_  2
#define S_  2048
#define DM_ 2048
#define H_  16
#define DH_ 128

static __device__ __forceinline__ float b2f(ushort_t u) {
  __hip_bfloat16 h = *reinterpret_cast<__hip_bfloat16*>(&u);
  return __bfloat162float(h);
}
static __device__ __forceinline__ ushort_t f2b(float f) {
  __hip_bfloat16 h = __float2bfloat16(f);
  return *reinterpret_cast<ushort_t*>(&h);
}

// ---------------------------------------------------------------------------
// out[c][r] = bf16(in[r][colOff + c]); in is f32 [R][inC], out bf16 [64*gx][R].
// ---------------------------------------------------------------------------
__global__ __launch_bounds__(256) void transpose_f32_to_bf16T(const float* __restrict__ in,
                                                              ushort_t* __restrict__ out,
                                                              int R, int inC, int colOff) {
  __shared__ ushort_t tile[64][72];  // +8 pad breaks bank conflicts
  const int tid = threadIdx.x;
  const int r0 = blockIdx.y * 64, c0 = blockIdx.x * 64;
#pragma unroll
  for (int p = 0; p < 2; ++p) {
    int li = tid + p * 256;
    int r = li >> 3, cs = (li & 7) * 8;
    const float* src = in + (size_t)(r0 + r) * inC + colOff + c0 + cs;
    float4 a = *(const float4*)src;
    float4 b = *(const float4*)(src + 4);
    ushort_t tmp[8] = {f2b(a.x), f2b(a.y), f2b(a.z), f2b(a.w),
                       f2b(b.x), f2b(b.y), f2b(b.z), f2b(b.w)};
    *(uint4*)&tile[r][cs] = *(const uint4*)tmp;
  }
  __syncthreads();
#pragma unroll
  for (int p = 0; p < 2; ++p) {
    int li = tid + p * 256;
    int cR = li >> 3, rs = (li & 7) * 8;
    ushort_t tmp[8];
#pragma unroll
    for (int e = 0; e < 8; ++e) tmp[e] = tile[rs + e][cR];
    *(uint4*)(out + (size_t)(c0 + cR) * R + r0 + rs) = *(const uint4*)tmp;
  }
}

// ---------------------------------------------------------------------------
// In-place transpose of a square NxN (N=2048) bf16 matrix, per z-batch.
// ---------------------------------------------------------------------------
__global__ __launch_bounds__(256) void transpose_inplace(ushort_t* __restrict__ M) {
  const int N = S_;
  const int ti = blockIdx.y, tj = blockIdx.x;
  if (tj < ti) return;
  ushort_t* Mb = M + (size_t)blockIdx.z * N * N;
  __shared__ ushort_t Ta[64][72], Tb[64][72];
  const int tid = threadIdx.x;
  const int r0 = ti * 64, c0 = tj * 64;
  const bool diag = (ti == tj);
#pragma unroll
  for (int p = 0; p < 2; ++p) {
    int li = tid + p * 256;
    int r = li >> 3, cs = (li & 7) * 8;
    *(uint4*)&Ta[r][cs] = *(const uint4*)(Mb + (size_t)(r0 + r) * N + c0 + cs);
    if (!diag)
      *(uint4*)&Tb[r][cs] = *(const uint4*)(Mb + (size_t)(c0 + r) * N + r0 + cs);
  }
  __syncthreads();
#pragma unroll
  for (int p = 0; p < 2; ++p) {
    int li = tid + p * 256;
    int cR = li >> 3, rs = (li & 7) * 8;
    ushort_t t1[8];
#pragma unroll
    for (int e = 0; e < 8; ++e) t1[e] = Ta[rs + e][cR];
    *(uint4*)(Mb + (size_t)(c0 + cR) * N + r0 + rs) = *(const uint4*)t1;
    if (!diag) {
      ushort_t t2[8];
#pragma unroll
      for (int e = 0; e < 8; ++e) t2[e] = Tb[rs + e][cR];
      *(uint4*)(Mb + (size_t)(r0 + cR) * N + c0 + rs) = *(const uint4*)t2;
    }
  }
}

// ---------------------------------------------------------------------------
// C[M,N] = A[M,K] * Bt[N,K]^T. A: f32 or bf16 (A_F32). Bt: bf16.
// C: f32 or bf16 (C_F32). fp32 accumulate. 128x128 tile, BK=32, 4 waves 2x2.
// ---------------------------------------------------------------------------
template <bool A_F32, bool C_F32>
__global__ __launch_bounds__(256) void gemm_bt(const void* __restrict__ Av,
                                               const ushort_t* __restrict__ Bt,
                                               void* __restrict__ Cv,
                                               int M, int N, int K) {
  __shared__ ushort_t As[128 * 40];  // 32 + 8 pad, rows 80B
  __shared__ ushort_t Bs[128 * 40];
  const int tid = threadIdx.x;
  const int wave = tid >> 6, lane = tid & 63;
  const int l15 = lane & 15, quad = lane >> 4;
  const int wr = (wave >> 1) * 64, wc = (wave & 1) * 64;
  const size_t m0 = (size_t)blockIdx.y * 128, n0 = (size_t)blockIdx.x * 128;

  floatx4 zero = {0.f, 0.f, 0.f, 0.f};
  floatx4 acc[4][4];
#pragma unroll
  for (int i = 0; i < 4; ++i)
#pragma unroll
    for (int j = 0; j < 4; ++j) acc[i][j] = zero;

  for (int kt = 0; kt < K; kt += 32) {
#pragma unroll
    for (int p = 0; p < 2; ++p) {
      int li = tid + p * 256;
      int row = li >> 2, seg = (li & 3) * 8;
      if (A_F32) {
        const float* src = (const float*)Av + (m0 + row) * K + kt + seg;
        float4 a = *(const float4*)src;
        float4 b = *(const float4*)(src + 4);
        ushort_t tmp[8] = {f2b(a.x), f2b(a.y), f2b(a.z), f2b(a.w),
                           f2b(b.x), f2b(b.y), f2b(b.z), f2b(b.w)};
        *(uint4*)&As[row * 40 + seg] = *(const uint4*)tmp;
      } else {
        *(uint4*)&As[row * 40 + seg] =
            *(const uint4*)((const ushort_t*)Av + (m0 + row) * K + kt + seg);
      }
      *(uint4*)&Bs[row * 40 + seg] = *(const uint4*)(Bt + (n0 + row) * K + kt + seg);
    }
    __syncthreads();
    short8 af[4], bf[4];
#pragma unroll
    for (int i = 0; i < 4; ++i)
      af[i] = *(const short8*)&As[(wr + i * 16 + l15) * 40 + quad * 8];
#pragma unroll
    for (int j = 0; j < 4; ++j)
      bf[j] = *(const short8*)&Bs[(wc + j * 16 + l15) * 40 + quad * 8];
#pragma unroll
    for (int i = 0; i < 4; ++i)
#pragma unroll
      for (int j = 0; j < 4; ++j)
        acc[i][j] = __builtin_amdgcn_mfma_f32_16x16x32_bf16(af[i], bf[j], acc[i][j], 0, 0, 0);
    __syncthreads();
  }
#pragma unroll
  for (int i = 0; i < 4; ++i)
#pragma unroll
    for (int j = 0; j < 4; ++j)
#pragma unroll
      for (int r = 0; r < 4; ++r) {
        size_t row = m0 + wr + i * 16 + quad * 4 + r;
        size_t col = n0 + wc + j * 16 + l15;
        if (C_F32)
          ((float*)Cv)[row * N + col] = acc[i][j][r];
        else
          ((ushort_t*)Cv)[row * N + col] = f2b(acc[i][j][r]);
      }
}

// ---------------------------------------------------------------------------
// unit-norm + RoPE (even heads) + gain-fold, IN PLACE on bf16 Q/K buffers of
// layout [b][s][h*d]. One wave per (b,s,h); lane = dim, handles d and d+64.
// ---------------------------------------------------------------------------
__global__ __launch_bounds__(256) void norm_rope(ushort_t* __restrict__ Q,
                                                 ushort_t* __restrict__ Kb,
                                                 const float* __restrict__ gain) {
  const int tid = threadIdx.x;
  const int wave = tid >> 6, lane = tid & 63;
  const int idx = blockIdx.x * 4 + wave;  // ((b*S+s)*H + h)
  const int h = idx & 15;
  const int s = (idx >> 4) & (S_ - 1);
  const size_t off = (size_t)(idx >> 4) * DM_ + h * DH_;

  float q1 = b2f(Q[off + lane]),  q2 = b2f(Q[off + 64 + lane]);
  float k1 = b2f(Kb[off + lane]), k2 = b2f(Kb[off + 64 + lane]);

  float sq = q1 * q1 + q2 * q2;
  float sk = k1 * k1 + k2 * k2;
#pragma unroll
  for (int o = 1; o < 64; o <<= 1) {
    sq += __shfl_xor(sq, o, 64);
    sk += __shfl_xor(sk, o, 64);
  }
  float rq = rsqrtf(sq + 1e-6f), rk = rsqrtf(sk + 1e-6f);
  q1 *= rq; q2 *= rq; k1 *= rk; k2 *= rk;

  float qo1 = q1, qo2 = q2, ko1 = k1, ko2 = k2;
  if ((h & 1) == 0) {  // ROPE_MASK tiles [1,0] over heads: even heads roped
    float invf = powf(10000.0f, -(float)lane * (1.0f / 64.0f));
    float th = (float)s * invf;
    float c = cosf(th), sn = sinf(th);  // accurate range reduction (th up to ~2047)
    qo1 = q1 * c - q2 * sn;  qo2 = q1 * sn + q2 * c;
    ko1 = k1 * c - k2 * sn;  ko2 = k1 * sn + k2 * c;
  }
  float g = gain[h];
  qo1 *= g; qo2 *= g;

  Q[off + lane]       = f2b(qo1);
  Q[off + 64 + lane]  = f2b(qo2);
  Kb[off + lane]      = f2b(ko1);
  Kb[off + 64 + lane] = f2b(ko2);
}

// ---------------------------------------------------------------------------
// Flash-style causal attention (bf16). Q,K: [b][s][h*d] normalized. V:
// transposed in place to [b][h*d][s]. Y written in place over Q (regions are
// block-exclusive; Q tile staged to LDS first). 4 waves, 64 Q-rows/block.
// ---------------------------------------------------------------------------
__global__ __launch_bounds__(256) void attn(ushort_t* __restrict__ QY,
                                            const ushort_t* __restrict__ Kg,
                                            const ushort_t* __restrict__ Vg) {
  constexpr int AD = 136;  // 128 + 8 pad
  constexpr int VD = 72;   // 64 + 8 pad
  __shared__ ushort_t Qs[64 * AD];
  __shared__ ushort_t Ks[64 * AD];
  __shared__ ushort_t Vs[128 * VD];
  __shared__ ushort_t Ps[4 * 16 * VD];

  const int tid = threadIdx.x;
  const int wave = tid >> 6, lane = tid & 63;
  const int l15 = lane & 15, quad = lane >> 4;
  const int bh = blockIdx.y;
  const int b = bh >> 4, h = bh & 15;
  const int qt = blockIdx.x, q0 = qt * 64;

  ushort_t* Qg        = QY + (size_t)(b * S_ + q0) * DM_ + h * DH_;
  const ushort_t* Kgb = Kg + (size_t)b * S_ * DM_ + h * DH_;
  const ushort_t* Vgb = Vg + (size_t)b * S_ * DM_ + (size_t)(h * DH_) * S_;  // [dim][s]

#pragma unroll
  for (int p = 0; p < 4; ++p) {
    int li = tid + p * 256;
    int r = li >> 4, seg = (li & 15) * 8;
    *(uint4*)&Qs[r * AD + seg] = *(const uint4*)(Qg + (size_t)r * DM_ + seg);
  }
  __syncthreads();
  short8 aq[4];
#pragma unroll
  for (int ks = 0; ks < 4; ++ks)
    aq[ks] = *(const short8*)&Qs[(wave * 16 + l15) * AD + ks * 32 + quad * 8];

  float mrow[4], lrow[4];
  floatx4 zero = {0.f, 0.f, 0.f, 0.f};
  floatx4 oacc[8];
#pragma unroll
  for (int r = 0; r < 4; ++r) { mrow[r] = -1e30f; lrow[r] = 0.f; }
#pragma unroll
  for (int d = 0; d < 8; ++d) oacc[d] = zero;

  for (int kt = 0; kt <= qt; ++kt) {
    __syncthreads();
#pragma unroll
    for (int p = 0; p < 4; ++p) {
      int li = tid + p * 256;
      int r = li >> 4, seg = (li & 15) * 8;
      *(uint4*)&Ks[r * AD + seg] =
          *(const uint4*)(Kgb + (size_t)(kt * 64 + r) * DM_ + seg);
    }
#pragma unroll
    for (int p = 0; p < 4; ++p) {
      int li = tid + p * 256;
      int d = li >> 3, seg = (li & 7) * 8;
      *(uint4*)&Vs[d * VD + seg] =
          *(const uint4*)(Vgb + (size_t)d * S_ + kt * 64 + seg);
    }
    __syncthreads();

    floatx4 sacc[4];
#pragma unroll
    for (int j = 0; j < 4; ++j) sacc[j] = zero;
#pragma unroll
    for (int ks = 0; ks < 4; ++ks) {
#pragma unroll
      for (int j = 0; j < 4; ++j) {
        short8 bk = *(const short8*)&Ks[(j * 16 + l15) * AD + ks * 32 + quad * 8];
        sacc[j] = __builtin_amdgcn_mfma_f32_16x16x32_bf16(aq[ks], bk, sacc[j], 0, 0, 0);
      }
    }
    if (kt == qt) {
#pragma unroll
      for (int j = 0; j < 4; ++j)
#pragma unroll
        for (int r = 0; r < 4; ++r) {
          int key = j * 16 + l15;
          int qr = wave * 16 + quad * 4 + r;
          if (key > qr) sacc[j][r] = -1e30f;
        }
    }
    float alpha[4];
#pragma unroll
    for (int r = 0; r < 4; ++r) {
      float mx = fmaxf(fmaxf(sacc[0][r], sacc[1][r]), fmaxf(sacc[2][r], sacc[3][r]));
#pragma unroll
      for (int o = 1; o < 16; o <<= 1) mx = fmaxf(mx, __shfl_xor(mx, o, 64));
      float mi = fmaxf(mrow[r], mx);
      alpha[r] = __expf(mrow[r] - mi);
      mrow[r] = mi;
      float rs = 0.f;
#pragma unroll
      for (int j = 0; j < 4; ++j) {
        float p = __expf(sacc[j][r] - mi);
        sacc[j][r] = p;
        rs += p;
      }
#pragma unroll
      for (int o = 1; o < 16; o <<= 1) rs += __shfl_xor(rs, o, 64);
      lrow[r] = lrow[r] * alpha[r] + rs;
    }
#pragma unroll
    for (int j = 0; j < 4; ++j)
#pragma unroll
      for (int r = 0; r < 4; ++r)
        Ps[wave * 16 * VD + (quad * 4 + r) * VD + j * 16 + l15] = f2b(sacc[j][r]);
    __syncthreads();

#pragma unroll
    for (int d = 0; d < 8; ++d)
#pragma unroll
      for (int r = 0; r < 4; ++r) oacc[d][r] *= alpha[r];
#pragma unroll
    for (int ks2 = 0; ks2 < 2; ++ks2) {
      short8 ap = *(const short8*)&Ps[wave * 16 * VD + l15 * VD + ks2 * 32 + quad * 8];
#pragma unroll
      for (int d = 0; d < 8; ++d) {
        short8 bv = *(const short8*)&Vs[(d * 16 + l15) * VD + ks2 * 32 + quad * 8];
        oacc[d] = __builtin_amdgcn_mfma_f32_16x16x32_bf16(ap, bv, oacc[d], 0, 0, 0);
      }
    }
  }

#pragma unroll
  for (int r = 0; r < 4; ++r) {
    float inv = 1.0f / lrow[r];
    size_t row = (size_t)(b * S_ + q0 + wave * 16 + quad * 4 + r);
#pragma unroll
    for (int d = 0; d < 8; ++d) {
      size_t col = (size_t)h * DH_ + d * 16 + l15;
      QY[row * DM_ + col] = f2b(oacc[d][r] * inv);
    }
  }
}

// ---------------------------------------------------------------------------
extern "C" void kernel_launch(void* const* d_in, const int* in_sizes, int n_in,
                              void* d_out, int out_size, void* d_ws, size_t ws_size,
                              hipStream_t stream) {
  const float* x      = (const float*)d_in[0];
  const float* w_qkv  = (const float*)d_in[1];
  const float* w_out  = (const float*)d_in[2];
  const float* q_gain = (const float*)d_in[3];
  float* out = (float*)d_out;

  // Workspace: 3 x 16.8 MB (Q/K/V bf16) + 8.4 MB (bf16 transposed weight)
  char* ws = (char*)d_ws;
  const size_t bsd = (size_t)B_ * S_ * DM_;
  ushort_t* Qraw = (ushort_t*)ws;
  ushort_t* Kraw = Qraw + bsd;
  ushort_t* Vraw = Kraw + bsd;
  ushort_t* wT   = Vraw + bsd;  // 2048x2048 bf16
  ushort_t* bufs[3] = {Qraw, Kraw, Vraw};

  // QKV projection, one 2048-wide slice at a time (wT reused; stream-ordered)
  for (int i = 0; i < 3; ++i) {
    transpose_f32_to_bf16T<<<dim3(32, 32), 256, 0, stream>>>(w_qkv, wT, DM_, 3 * DM_, i * DM_);
    gemm_bt<true, false><<<dim3(16, 32), 256, 0, stream>>>(x, wT, bufs[i], B_ * S_, DM_, DM_);
  }
  // w_out -> bf16 transposed into wT
  transpose_f32_to_bf16T<<<dim3(32, 32), 256, 0, stream>>>(w_out, wT, DM_, DM_, 0);
  // norm + rope + gain, in place
  norm_rope<<<dim3(B_ * S_ * H_ / 4), 256, 0, stream>>>(Qraw, Kraw, q_gain);
  // V -> V^T in place (per batch, square)
  transpose_inplace<<<dim3(32, 32, B_), 256, 0, stream>>>(Vraw);
  // causal attention; Y overwrites Qraw
  attn<<<dim3(S_ / 64, B_ * H_), 256, 0, stream>>>(Qraw, Kraw, Vraw);
  // out = Y @ w_out (f32 output)
  gemm_bt<false, true><<<dim3(16, 32), 256, 0, stream>>>(Qraw, wT, out, B_ * S_, DM_, DM_);
}

// Round 4
// 488.744 us; speedup vs baseline: 1.2787x; 1.2787x over previous
//
#include <hip/hip_runtime.h>
#include <hip/hip_bf16.h>

typedef unsigned short ushort_t;
typedef __attribute__((ext_vector_type(8))) short short8;
typedef __attribute__((ext_vector_type(4))) float floatx4;

#define B_  2
#define S_  2048
#define DM_ 2048
#define H_  16
#define DH_ 128

#define AS1(p) ((const __attribute__((address_space(1))) void*)(p))
#define AS3(p) ((__attribute__((address_space(3))) void*)(p))

static __device__ __forceinline__ float b2f(ushort_t u) {
  __hip_bfloat16 h = *reinterpret_cast<__hip_bfloat16*>(&u);
  return __bfloat162float(h);
}
static __device__ __forceinline__ ushort_t f2b(float f) {
  __hip_bfloat16 h = __float2bfloat16(f);
  return *reinterpret_cast<ushort_t*>(&h);
}

// ---------------------------------------------------------------------------
// x (f32) -> bf16, 8 elems/thread.
// ---------------------------------------------------------------------------
__global__ __launch_bounds__(256) void convert_f32_bf16(const float* __restrict__ in,
                                                        ushort_t* __restrict__ out) {
  size_t i = ((size_t)blockIdx.x * 256 + threadIdx.x) * 8;
  float4 a = *(const float4*)(in + i);
  float4 b = *(const float4*)(in + i + 4);
  ushort_t tmp[8] = {f2b(a.x), f2b(a.y), f2b(a.z), f2b(a.w),
                     f2b(b.x), f2b(b.y), f2b(b.z), f2b(b.w)};
  *(uint4*)(out + i) = *(const uint4*)tmp;
}

// ---------------------------------------------------------------------------
// out[c][r] = bf16(in[r][colOff + c]); in f32 [R][inC], out bf16 [64*gx][R].
// ---------------------------------------------------------------------------
__global__ __launch_bounds__(256) void transpose_f32_to_bf16T(const float* __restrict__ in,
                                                              ushort_t* __restrict__ out,
                                                              int R, int inC, int colOff) {
  __shared__ ushort_t tile[64][72];
  const int tid = threadIdx.x;
  const int r0 = blockIdx.y * 64, c0 = blockIdx.x * 64;
#pragma unroll
  for (int p = 0; p < 2; ++p) {
    int li = tid + p * 256;
    int r = li >> 3, cs = (li & 7) * 8;
    const float* src = in + (size_t)(r0 + r) * inC + colOff + c0 + cs;
    float4 a = *(const float4*)src;
    float4 b = *(const float4*)(src + 4);
    ushort_t tmp[8] = {f2b(a.x), f2b(a.y), f2b(a.z), f2b(a.w),
                       f2b(b.x), f2b(b.y), f2b(b.z), f2b(b.w)};
    *(uint4*)&tile[r][cs] = *(const uint4*)tmp;
  }
  __syncthreads();
#pragma unroll
  for (int p = 0; p < 2; ++p) {
    int li = tid + p * 256;
    int cR = li >> 3, rs = (li & 7) * 8;
    ushort_t tmp[8];
#pragma unroll
    for (int e = 0; e < 8; ++e) tmp[e] = tile[rs + e][cR];
    *(uint4*)(out + (size_t)(c0 + cR) * R + r0 + rs) = *(const uint4*)tmp;
  }
}

// ---------------------------------------------------------------------------
// In-place transpose of square 2048x2048 bf16, per z-batch.
// ---------------------------------------------------------------------------
__global__ __launch_bounds__(256) void transpose_inplace(ushort_t* __restrict__ M) {
  const int N = S_;
  const int ti = blockIdx.y, tj = blockIdx.x;
  if (tj < ti) return;
  ushort_t* Mb = M + (size_t)blockIdx.z * N * N;
  __shared__ ushort_t Ta[64][72], Tb[64][72];
  const int tid = threadIdx.x;
  const int r0 = ti * 64, c0 = tj * 64;
  const bool diag = (ti == tj);
#pragma unroll
  for (int p = 0; p < 2; ++p) {
    int li = tid + p * 256;
    int r = li >> 3, cs = (li & 7) * 8;
    *(uint4*)&Ta[r][cs] = *(const uint4*)(Mb + (size_t)(r0 + r) * N + c0 + cs);
    if (!diag)
      *(uint4*)&Tb[r][cs] = *(const uint4*)(Mb + (size_t)(c0 + r) * N + r0 + cs);
  }
  __syncthreads();
#pragma unroll
  for (int p = 0; p < 2; ++p) {
    int li = tid + p * 256;
    int cR = li >> 3, rs = (li & 7) * 8;
    ushort_t t1[8];
#pragma unroll
    for (int e = 0; e < 8; ++e) t1[e] = Ta[rs + e][cR];
    *(uint4*)(Mb + (size_t)(c0 + cR) * N + r0 + rs) = *(const uint4*)t1;
    if (!diag) {
      ushort_t t2[8];
#pragma unroll
      for (int e = 0; e < 8; ++e) t2[e] = Tb[rs + e][cR];
      *(uint4*)(Mb + (size_t)(r0 + cR) * N + c0 + rs) = *(const uint4*)t2;
    }
  }
}

// ---------------------------------------------------------------------------
// m97-style GEMM: C[M,N] = A[M,K] * Bt[N,K]^T, bf16 in, fp32 acc.
// global_load_lds width-16 staging, unpadded 128x32 LDS tiles.
// ---------------------------------------------------------------------------
template <bool C_F32>
__global__ __launch_bounds__(256) void gemm_bt_async(const ushort_t* __restrict__ A,
                                                     const ushort_t* __restrict__ Bt,
                                                     void* __restrict__ Cv,
                                                     int M, int N, int K) {
  __shared__ alignas(16) ushort_t As[128 * 32];
  __shared__ alignas(16) ushort_t Bs[128 * 32];
  const int tid = threadIdx.x;
  const int wave = tid >> 6, lane = tid & 63;
  const int l15 = lane & 15, quad = lane >> 4;
  const int wr = (wave >> 1) * 64, wc = (wave & 1) * 64;
  const size_t m0 = (size_t)blockIdx.y * 128, n0 = (size_t)blockIdx.x * 128;
  const int srow = lane >> 2, scol = (lane & 3) * 8;  // within 16-row chunk

  floatx4 zero = {0.f, 0.f, 0.f, 0.f};
  floatx4 acc[4][4];
#pragma unroll
  for (int i = 0; i < 4; ++i)
#pragma unroll
    for (int j = 0; j < 4; ++j) acc[i][j] = zero;

  for (int kt = 0; kt < K; kt += 32) {
#pragma unroll
    for (int i = 0; i < 2; ++i) {
      int c = wave * 2 + i;          // chunk 0..7, 16 rows each
      int row = c * 16 + srow;
      __builtin_amdgcn_global_load_lds(AS1(A + (m0 + row) * K + kt + scol),
                                       AS3((char*)As + c * 1024), 16, 0, 0);
      __builtin_amdgcn_global_load_lds(AS1(Bt + (n0 + row) * K + kt + scol),
                                       AS3((char*)Bs + c * 1024), 16, 0, 0);
    }
    __syncthreads();
    short8 af[4], bf[4];
#pragma unroll
    for (int i = 0; i < 4; ++i)
      af[i] = *(const short8*)&As[(wr + i * 16 + l15) * 32 + quad * 8];
#pragma unroll
    for (int j = 0; j < 4; ++j)
      bf[j] = *(const short8*)&Bs[(wc + j * 16 + l15) * 32 + quad * 8];
#pragma unroll
    for (int i = 0; i < 4; ++i)
#pragma unroll
      for (int j = 0; j < 4; ++j)
        acc[i][j] = __builtin_amdgcn_mfma_f32_16x16x32_bf16(af[i], bf[j], acc[i][j], 0, 0, 0);
    __syncthreads();
  }
#pragma unroll
  for (int i = 0; i < 4; ++i)
#pragma unroll
    for (int j = 0; j < 4; ++j)
#pragma unroll
      for (int r = 0; r < 4; ++r) {
        size_t row = m0 + wr + i * 16 + quad * 4 + r;
        size_t col = n0 + wc + j * 16 + l15;
        if (C_F32)
          ((float*)Cv)[row * N + col] = acc[i][j][r];
        else
          ((ushort_t*)Cv)[row * N + col] = f2b(acc[i][j][r]);
      }
}

// ---------------------------------------------------------------------------
// unit-norm + RoPE (even heads) + gain-fold, in place. One wave per (b,s,h).
// ---------------------------------------------------------------------------
__global__ __launch_bounds__(256) void norm_rope(ushort_t* __restrict__ Q,
                                                 ushort_t* __restrict__ Kb,
                                                 const float* __restrict__ gain) {
  const int tid = threadIdx.x;
  const int wave = tid >> 6, lane = tid & 63;
  const int idx = blockIdx.x * 4 + wave;  // ((b*S+s)*H + h)
  const int h = idx & 15;
  const int s = (idx >> 4) & (S_ - 1);
  const size_t off = (size_t)(idx >> 4) * DM_ + h * DH_;

  float q1 = b2f(Q[off + lane]),  q2 = b2f(Q[off + 64 + lane]);
  float k1 = b2f(Kb[off + lane]), k2 = b2f(Kb[off + 64 + lane]);

  float sq = q1 * q1 + q2 * q2;
  float sk = k1 * k1 + k2 * k2;
#pragma unroll
  for (int o = 1; o < 64; o <<= 1) {
    sq += __shfl_xor(sq, o, 64);
    sk += __shfl_xor(sk, o, 64);
  }
  float rq = rsqrtf(sq + 1e-6f), rk = rsqrtf(sk + 1e-6f);
  q1 *= rq; q2 *= rq; k1 *= rk; k2 *= rk;

  float qo1 = q1, qo2 = q2, ko1 = k1, ko2 = k2;
  if ((h & 1) == 0) {
    float invf = powf(10000.0f, -(float)lane * (1.0f / 64.0f));
    float th = (float)s * invf;
    float c = cosf(th), sn = sinf(th);
    qo1 = q1 * c - q2 * sn;  qo2 = q1 * sn + q2 * c;
    ko1 = k1 * c - k2 * sn;  ko2 = k1 * sn + k2 * c;
  }
  float g = gain[h];
  qo1 *= g; qo2 *= g;

  Q[off + lane]       = f2b(qo1);
  Q[off + 64 + lane]  = f2b(qo2);
  Kb[off + lane]      = f2b(ko1);
  Kb[off + 64 + lane] = f2b(ko2);
}

// ---------------------------------------------------------------------------
// Balanced-pair flash attention. Block (p, bh) handles Q-tiles {p, 31-p}
// (64 rows each) with shared K/V staging over kt = 0..31-p. K/V staged via
// global_load_lds into unpadded XOR-swizzled LDS (seg ^= row&7). Q fragments
// loaded straight to registers. Y written in place over Q.
// ---------------------------------------------------------------------------
__global__ __launch_bounds__(256, 2) void attn(ushort_t* __restrict__ QY,
                                               const ushort_t* __restrict__ Kg,
                                               const ushort_t* __restrict__ Vg) {
  __shared__ alignas(16) ushort_t Ks[64 * 128];   // [key][dim], swizzled
  __shared__ alignas(16) ushort_t Vs[128 * 64];   // [dim][key], swizzled
  __shared__ ushort_t Ps[2 * 4 * 16 * 72];        // [tile][wave][row][64+8]

  const int tid = threadIdx.x;
  const int wave = tid >> 6, lane = tid & 63;
  const int l15 = lane & 15, quad = lane >> 4;
  const int bh = blockIdx.y;
  const int b = bh >> 4, h = bh & 15;
  const int p = blockIdx.x;
  const int qt[2] = {p, 31 - p};

  const ushort_t* Kgb = Kg + (size_t)b * S_ * DM_ + h * DH_;
  const ushort_t* Vgb = Vg + (size_t)b * S_ * DM_ + (size_t)(h * DH_) * S_;

  // Q fragments for both tiles, straight from global
  short8 aq[2][4];
#pragma unroll
  for (int t = 0; t < 2; ++t) {
    const ushort_t* Qg = QY + (size_t)(b * S_ + qt[t] * 64 + wave * 16 + l15) * DM_ + h * DH_;
#pragma unroll
    for (int ks = 0; ks < 4; ++ks)
      aq[t][ks] = *(const short8*)(Qg + ks * 32 + quad * 8);
  }

  float mrow[2][4], lrow[2][4];
  floatx4 zero = {0.f, 0.f, 0.f, 0.f};
  floatx4 oacc[2][8];
#pragma unroll
  for (int t = 0; t < 2; ++t) {
#pragma unroll
    for (int r = 0; r < 4; ++r) { mrow[t][r] = -1e30f; lrow[t][r] = 0.f; }
#pragma unroll
    for (int d = 0; d < 8; ++d) oacc[t][d] = zero;
  }

  // staging lane decode
  const int krow_in = lane >> 4, ksd = lane & 15;   // K: 16 lanes/row (256B)
  const int vrow_in = lane >> 3, vsd = lane & 7;    // V: 8 lanes/row (128B)

  for (int kt = 0; kt <= qt[1]; ++kt) {
    __syncthreads();  // prior iteration's LDS reads complete
#pragma unroll
    for (int i = 0; i < 4; ++i) {
      int c = wave * 4 + i;  // 0..15
      {  // K chunk: 4 rows of 128 elems
        int r = c * 4 + krow_in;
        int sg = ksd ^ (r & 7);
        __builtin_amdgcn_global_load_lds(AS1(Kgb + (size_t)(kt * 64 + r) * DM_ + sg * 8),
                                         AS3((char*)Ks + c * 1024), 16, 0, 0);
      }
      {  // V chunk: 8 rows of 64 elems
        int r = c * 8 + vrow_in;
        int sg = vsd ^ (r & 7);
        __builtin_amdgcn_global_load_lds(AS1(Vgb + (size_t)r * S_ + kt * 64 + sg * 8),
                                         AS3((char*)Vs + c * 1024), 16, 0, 0);
      }
    }
    __syncthreads();

    float alpha[2][4];
#pragma unroll
    for (int t = 0; t < 2; ++t) {
      if (t == 0 && kt > qt[0]) continue;  // lo tile finished (uniform branch)
      floatx4 sacc[4];
#pragma unroll
      for (int j = 0; j < 4; ++j) sacc[j] = zero;
#pragma unroll
      for (int ks = 0; ks < 4; ++ks) {
#pragma unroll
        for (int j = 0; j < 4; ++j) {
          int row = j * 16 + l15;
          int sl = (ks * 4 + quad) ^ (row & 7);  // swizzled seg
          short8 bk = *(const short8*)&Ks[row * 128 + sl * 8];
          sacc[j] = __builtin_amdgcn_mfma_f32_16x16x32_bf16(aq[t][ks], bk, sacc[j], 0, 0, 0);
        }
      }
      if (kt == qt[t]) {  // diagonal tile causal mask
#pragma unroll
        for (int j = 0; j < 4; ++j)
#pragma unroll
          for (int r = 0; r < 4; ++r) {
            int key = j * 16 + l15;
            int qr = wave * 16 + quad * 4 + r;
            if (key > qr) sacc[j][r] = -1e30f;
          }
      }
#pragma unroll
      for (int r = 0; r < 4; ++r) {
        float mx = fmaxf(fmaxf(sacc[0][r], sacc[1][r]), fmaxf(sacc[2][r], sacc[3][r]));
#pragma unroll
        for (int o = 1; o < 16; o <<= 1) mx = fmaxf(mx, __shfl_xor(mx, o, 64));
        float mi = fmaxf(mrow[t][r], mx);
        alpha[t][r] = __expf(mrow[t][r] - mi);
        mrow[t][r] = mi;
        float rs = 0.f;
#pragma unroll
        for (int j = 0; j < 4; ++j) {
          float pv = __expf(sacc[j][r] - mi);
          sacc[j][r] = pv;
          rs += pv;
        }
#pragma unroll
        for (int o = 1; o < 16; o <<= 1) rs += __shfl_xor(rs, o, 64);
        lrow[t][r] = lrow[t][r] * alpha[t][r] + rs;
      }
#pragma unroll
      for (int j = 0; j < 4; ++j)
#pragma unroll
        for (int r = 0; r < 4; ++r)
          Ps[((t * 4 + wave) * 16 + quad * 4 + r) * 72 + j * 16 + l15] = f2b(sacc[j][r]);
    }
    __syncthreads();

#pragma unroll
    for (int t = 0; t < 2; ++t) {
      if (t == 0 && kt > qt[0]) continue;
#pragma unroll
      for (int d = 0; d < 8; ++d)
#pragma unroll
        for (int r = 0; r < 4; ++r) oacc[t][d][r] *= alpha[t][r];
#pragma unroll
      for (int ks2 = 0; ks2 < 2; ++ks2) {
        short8 ap = *(const short8*)&Ps[((t * 4 + wave) * 16 + l15) * 72 + ks2 * 32 + quad * 8];
#pragma unroll
        for (int d = 0; d < 8; ++d) {
          int row = d * 16 + l15;
          int sl = (ks2 * 4 + quad) ^ (row & 7);
          short8 bv = *(const short8*)&Vs[row * 64 + sl * 8];
          oacc[t][d] = __builtin_amdgcn_mfma_f32_16x16x32_bf16(ap, bv, oacc[t][d], 0, 0, 0);
        }
      }
    }
  }

#pragma unroll
  for (int t = 0; t < 2; ++t) {
#pragma unroll
    for (int r = 0; r < 4; ++r) {
      float inv = 1.0f / lrow[t][r];
      size_t row = (size_t)(b * S_ + qt[t] * 64 + wave * 16 + quad * 4 + r);
#pragma unroll
      for (int d = 0; d < 8; ++d) {
        size_t col = (size_t)h * DH_ + d * 16 + l15;
        QY[row * DM_ + col] = f2b(oacc[t][d][r] * inv);
      }
    }
  }
}

// ---------------------------------------------------------------------------
extern "C" void kernel_launch(void* const* d_in, const int* in_sizes, int n_in,
                              void* d_out, int out_size, void* d_ws, size_t ws_size,
                              hipStream_t stream) {
  const float* x      = (const float*)d_in[0];
  const float* w_qkv  = (const float*)d_in[1];
  const float* w_out  = (const float*)d_in[2];
  const float* q_gain = (const float*)d_in[3];
  float* out = (float*)d_out;

  // ws: Q/K/V bf16 (3 x 16.8 MB) + wT (8.4 MB) = 58.7 MB (proven size).
  // xbf (16.8 MB) lives in the d_out region until the final GEMM writes it.
  char* ws = (char*)d_ws;
  const size_t bsd = (size_t)B_ * S_ * DM_;
  ushort_t* Qraw = (ushort_t*)ws;
  ushort_t* Kraw = Qraw + bsd;
  ushort_t* Vraw = Kraw + bsd;
  ushort_t* wT   = Vraw + bsd;
  ushort_t* xbf  = (ushort_t*)d_out;
  ushort_t* bufs[3] = {Qraw, Kraw, Vraw};

  convert_f32_bf16<<<dim3(bsd / (8 * 256)), 256, 0, stream>>>(x, xbf);

  for (int i = 0; i < 3; ++i) {
    transpose_f32_to_bf16T<<<dim3(32, 32), 256, 0, stream>>>(w_qkv, wT, DM_, 3 * DM_, i * DM_);
    gemm_bt_async<false><<<dim3(16, 32), 256, 0, stream>>>(xbf, wT, bufs[i], B_ * S_, DM_, DM_);
  }
  transpose_f32_to_bf16T<<<dim3(32, 32), 256, 0, stream>>>(w_out, wT, DM_, DM_, 0);
  norm_rope<<<dim3(B_ * S_ * H_ / 4), 256, 0, stream>>>(Qraw, Kraw, q_gain);
  transpose_inplace<<<dim3(32, 32, B_), 256, 0, stream>>>(Vraw);
  attn<<<dim3(S_ / 128, B_ * H_), 256, 0, stream>>>(Qraw, Kraw, Vraw);
  gemm_bt_async<true><<<dim3(16, 32), 256, 0, stream>>>(Qraw, wT, out, B_ * S_, DM_, DM_);
}

// Round 5
// 474.908 us; speedup vs baseline: 1.3160x; 1.0291x over previous
//
#include <hip/hip_runtime.h>
#include <hip/hip_bf16.h>

typedef unsigned short ushort_t;
typedef __attribute__((ext_vector_type(8))) short short8;
typedef __attribute__((ext_vector_type(4))) float floatx4;

#define B_  2
#define S_  2048
#define DM_ 2048
#define H_  16
#define DH_ 128

#define AS1(p) ((const __attribute__((address_space(1))) void*)(p))
#define AS3(p) ((__attribute__((address_space(3))) void*)(p))

static __device__ __forceinline__ float b2f(ushort_t u) {
  __hip_bfloat16 h = *reinterpret_cast<__hip_bfloat16*>(&u);
  return __bfloat162float(h);
}
static __device__ __forceinline__ ushort_t f2b(float f) {
  __hip_bfloat16 h = __float2bfloat16(f);
  return *reinterpret_cast<ushort_t*>(&h);
}

// ---------------------------------------------------------------------------
// x (f32) -> bf16, 8 elems/thread.
// ---------------------------------------------------------------------------
__global__ __launch_bounds__(256) void convert_f32_bf16(const float* __restrict__ in,
                                                        ushort_t* __restrict__ out) {
  size_t i = ((size_t)blockIdx.x * 256 + threadIdx.x) * 8;
  float4 a = *(const float4*)(in + i);
  float4 b = *(const float4*)(in + i + 4);
  ushort_t tmp[8] = {f2b(a.x), f2b(a.y), f2b(a.z), f2b(a.w),
                     f2b(b.x), f2b(b.y), f2b(b.z), f2b(b.w)};
  *(uint4*)(out + i) = *(const uint4*)tmp;
}

// ---------------------------------------------------------------------------
// out[c][r] = bf16(in[r][colOff + c]); in f32 [R][inC], out bf16 [64*gx][R].
// ---------------------------------------------------------------------------
__global__ __launch_bounds__(256) void transpose_f32_to_bf16T(const float* __restrict__ in,
                                                              ushort_t* __restrict__ out,
                                                              int R, int inC, int colOff) {
  __shared__ ushort_t tile[64][72];
  const int tid = threadIdx.x;
  const int r0 = blockIdx.y * 64, c0 = blockIdx.x * 64;
#pragma unroll
  for (int p = 0; p < 2; ++p) {
    int li = tid + p * 256;
    int r = li >> 3, cs = (li & 7) * 8;
    const float* src = in + (size_t)(r0 + r) * inC + colOff + c0 + cs;
    float4 a = *(const float4*)src;
    float4 b = *(const float4*)(src + 4);
    ushort_t tmp[8] = {f2b(a.x), f2b(a.y), f2b(a.z), f2b(a.w),
                       f2b(b.x), f2b(b.y), f2b(b.z), f2b(b.w)};
    *(uint4*)&tile[r][cs] = *(const uint4*)tmp;
  }
  __syncthreads();
#pragma unroll
  for (int p = 0; p < 2; ++p) {
    int li = tid + p * 256;
    int cR = li >> 3, rs = (li & 7) * 8;
    ushort_t tmp[8];
#pragma unroll
    for (int e = 0; e < 8; ++e) tmp[e] = tile[rs + e][cR];
    *(uint4*)(out + (size_t)(c0 + cR) * R + r0 + rs) = *(const uint4*)tmp;
  }
}

// ---------------------------------------------------------------------------
// m97-style GEMM: C[M,N] = A[M,K] * Bt[N,K]^T, bf16 in, fp32 acc.
// MODE 0: C bf16, ld=N.  MODE 1: C f32, ld=N.
// MODE 2: C bf16 split: cols [0,2048) -> C0, [2048,4096) -> C1, ld=2048.
// ---------------------------------------------------------------------------
template <int MODE>
__global__ __launch_bounds__(256) void gemm_bt_async(const ushort_t* __restrict__ A,
                                                     const ushort_t* __restrict__ Bt,
                                                     void* __restrict__ C0,
                                                     void* __restrict__ C1,
                                                     int M, int N, int K) {
  __shared__ alignas(16) ushort_t As[128 * 32];
  __shared__ alignas(16) ushort_t Bs[128 * 32];
  const int tid = threadIdx.x;
  const int wave = tid >> 6, lane = tid & 63;
  const int l15 = lane & 15, quad = lane >> 4;
  const int wr = (wave >> 1) * 64, wc = (wave & 1) * 64;
  const size_t m0 = (size_t)blockIdx.y * 128, n0 = (size_t)blockIdx.x * 128;
  const int srow = lane >> 2, scol = (lane & 3) * 8;

  floatx4 zero = {0.f, 0.f, 0.f, 0.f};
  floatx4 acc[4][4];
#pragma unroll
  for (int i = 0; i < 4; ++i)
#pragma unroll
    for (int j = 0; j < 4; ++j) acc[i][j] = zero;

  for (int kt = 0; kt < K; kt += 32) {
#pragma unroll
    for (int i = 0; i < 2; ++i) {
      int c = wave * 2 + i;
      int row = c * 16 + srow;
      __builtin_amdgcn_global_load_lds(AS1(A + (m0 + row) * K + kt + scol),
                                       AS3((char*)As + c * 1024), 16, 0, 0);
      __builtin_amdgcn_global_load_lds(AS1(Bt + (n0 + row) * K + kt + scol),
                                       AS3((char*)Bs + c * 1024), 16, 0, 0);
    }
    __syncthreads();
    short8 af[4], bf[4];
#pragma unroll
    for (int i = 0; i < 4; ++i)
      af[i] = *(const short8*)&As[(wr + i * 16 + l15) * 32 + quad * 8];
#pragma unroll
    for (int j = 0; j < 4; ++j)
      bf[j] = *(const short8*)&Bs[(wc + j * 16 + l15) * 32 + quad * 8];
#pragma unroll
    for (int i = 0; i < 4; ++i)
#pragma unroll
      for (int j = 0; j < 4; ++j)
        acc[i][j] = __builtin_amdgcn_mfma_f32_16x16x32_bf16(af[i], bf[j], acc[i][j], 0, 0, 0);
    __syncthreads();
  }

  if (MODE == 2) {
    ushort_t* Cb = (n0 >= 2048) ? (ushort_t*)C1 : (ushort_t*)C0;
    size_t nc0 = n0 & 2047;
#pragma unroll
    for (int i = 0; i < 4; ++i)
#pragma unroll
      for (int j = 0; j < 4; ++j)
#pragma unroll
        for (int r = 0; r < 4; ++r) {
          size_t row = m0 + wr + i * 16 + quad * 4 + r;
          size_t col = nc0 + wc + j * 16 + l15;
          Cb[row * 2048 + col] = f2b(acc[i][j][r]);
        }
  } else {
#pragma unroll
    for (int i = 0; i < 4; ++i)
#pragma unroll
      for (int j = 0; j < 4; ++j)
#pragma unroll
        for (int r = 0; r < 4; ++r) {
          size_t row = m0 + wr + i * 16 + quad * 4 + r;
          size_t col = n0 + wc + j * 16 + l15;
          if (MODE == 1)
            ((float*)C0)[row * N + col] = acc[i][j][r];
          else
            ((ushort_t*)C0)[row * N + col] = f2b(acc[i][j][r]);
        }
  }
}

// ---------------------------------------------------------------------------
// unit-norm + RoPE (even heads) + gain-fold, in place. One wave per (b,s,h).
// ---------------------------------------------------------------------------
__global__ __launch_bounds__(256) void norm_rope(ushort_t* __restrict__ Q,
                                                 ushort_t* __restrict__ Kb,
                                                 const float* __restrict__ gain) {
  const int tid = threadIdx.x;
  const int wave = tid >> 6, lane = tid & 63;
  const int idx = blockIdx.x * 4 + wave;  // ((b*S+s)*H + h)
  const int h = idx & 15;
  const int s = (idx >> 4) & (S_ - 1);
  const size_t off = (size_t)(idx >> 4) * DM_ + h * DH_;

  float q1 = b2f(Q[off + lane]),  q2 = b2f(Q[off + 64 + lane]);
  float k1 = b2f(Kb[off + lane]), k2 = b2f(Kb[off + 64 + lane]);

  float sq = q1 * q1 + q2 * q2;
  float sk = k1 * k1 + k2 * k2;
#pragma unroll
  for (int o = 1; o < 64; o <<= 1) {
    sq += __shfl_xor(sq, o, 64);
    sk += __shfl_xor(sk, o, 64);
  }
  float rq = rsqrtf(sq + 1e-6f), rk = rsqrtf(sk + 1e-6f);
  q1 *= rq; q2 *= rq; k1 *= rk; k2 *= rk;

  float qo1 = q1, qo2 = q2, ko1 = k1, ko2 = k2;
  if ((h & 1) == 0) {  // ROPE_MASK tiles [1,0] over heads: even heads roped
    float invf = powf(10000.0f, -(float)lane * (1.0f / 64.0f));
    float th = (float)s * invf;
    float c = cosf(th), sn = sinf(th);
    qo1 = q1 * c - q2 * sn;  qo2 = q1 * sn + q2 * c;
    ko1 = k1 * c - k2 * sn;  ko2 = k1 * sn + k2 * c;
  }
  float g = gain[h];
  qo1 *= g; qo2 *= g;

  Q[off + lane]       = f2b(qo1);
  Q[off + 64 + lane]  = f2b(qo2);
  Kb[off + lane]      = f2b(ko1);
  Kb[off + 64 + lane] = f2b(ko2);
}

// ---------------------------------------------------------------------------
// Flash attention, fixed-max softmax. |logit| <= 12.1 by construction
// (unit q,k; gain=12), so p = exp(s - 13) needs NO running max / rescale.
// One 64-row Q-tile per block, longest-first (qt = 31 - bx), 1024 blocks.
// K/V/P in unpadded XOR-swizzled LDS (exactly 40 KB -> 4 blocks/CU).
// V layout: [dim][b*S+s] (row stride 4096). Y written in place over Q.
// ---------------------------------------------------------------------------
__global__ __launch_bounds__(256, 4) void attn(ushort_t* __restrict__ QY,
                                               const ushort_t* __restrict__ Kg,
                                               const ushort_t* __restrict__ Vg) {
  __shared__ alignas(16) ushort_t Ks[64 * 128];  // 16 KB [key][dim] swizzled
  __shared__ alignas(16) ushort_t Vs[128 * 64];  // 16 KB [dim][key] swizzled
  __shared__ alignas(16) ushort_t Ps[4 * 16 * 64];  // 8 KB, swizzled

  const float M0 = 13.0f;
  const int tid = threadIdx.x;
  const int wave = tid >> 6, lane = tid & 63;
  const int l15 = lane & 15, quad = lane >> 4;
  const int bh = blockIdx.y;
  const int b = bh >> 4, h = bh & 15;
  const int qt = (S_ / 64 - 1) - blockIdx.x;  // longest-first
  const int q0 = qt * 64;

  const ushort_t* Kgb = Kg + (size_t)b * S_ * DM_ + h * DH_;
  const ushort_t* Vgb = Vg + (size_t)(h * DH_) * (B_ * S_) + b * S_;

  // Q fragments straight from global
  short8 aq[4];
  {
    const ushort_t* Qg = QY + (size_t)(b * S_ + q0 + wave * 16 + l15) * DM_ + h * DH_;
#pragma unroll
    for (int ks = 0; ks < 4; ++ks)
      aq[ks] = *(const short8*)(Qg + ks * 32 + quad * 8);
  }

  float lsum[4] = {0.f, 0.f, 0.f, 0.f};
  floatx4 zero = {0.f, 0.f, 0.f, 0.f};
  floatx4 oacc[8];
#pragma unroll
  for (int d = 0; d < 8; ++d) oacc[d] = zero;

  const int krow_in = lane >> 4, ksd = lane & 15;  // K staging: 16 lanes/row
  const int vrow_in = lane >> 3, vsd = lane & 7;   // V staging: 8 lanes/row

  for (int kt = 0; kt <= qt; ++kt) {
    __syncthreads();  // prior iteration's LDS reads complete
#pragma unroll
    for (int i = 0; i < 4; ++i) {
      int c = wave * 4 + i;  // 0..15
      {  // K chunk: 4 rows x 128 dims
        int r = c * 4 + krow_in;
        int sg = ksd ^ (r & 7);
        __builtin_amdgcn_global_load_lds(AS1(Kgb + (size_t)(kt * 64 + r) * DM_ + sg * 8),
                                         AS3((char*)Ks + c * 1024), 16, 0, 0);
      }
      {  // V chunk: 8 rows x 64 keys
        int r = c * 8 + vrow_in;
        int sg = vsd ^ (r & 7);
        __builtin_amdgcn_global_load_lds(AS1(Vgb + (size_t)r * (B_ * S_) + kt * 64 + sg * 8),
                                         AS3((char*)Vs + c * 1024), 16, 0, 0);
      }
    }
    __syncthreads();

    floatx4 sacc[4];
#pragma unroll
    for (int j = 0; j < 4; ++j) sacc[j] = zero;
#pragma unroll
    for (int ks = 0; ks < 4; ++ks) {
#pragma unroll
      for (int j = 0; j < 4; ++j) {
        int row = j * 16 + l15;
        int sl = (ks * 4 + quad) ^ (row & 7);
        short8 bk = *(const short8*)&Ks[row * 128 + sl * 8];
        sacc[j] = __builtin_amdgcn_mfma_f32_16x16x32_bf16(aq[ks], bk, sacc[j], 0, 0, 0);
      }
    }
    if (kt == qt) {  // diagonal tile causal mask
#pragma unroll
      for (int j = 0; j < 4; ++j)
#pragma unroll
        for (int r = 0; r < 4; ++r) {
          int key = j * 16 + l15;
          int qr = wave * 16 + quad * 4 + r;
          if (key > qr) sacc[j][r] = -1e30f;
        }
    }
    // p = exp(s - M0); no max-tracking, no rescale; lane-local partial sums
#pragma unroll
    for (int j = 0; j < 4; ++j)
#pragma unroll
      for (int r = 0; r < 4; ++r) {
        float pv = __expf(sacc[j][r] - M0);
        sacc[j][r] = pv;
        lsum[r] += pv;
      }
    // P: C-layout -> swizzled LDS -> A-layout
#pragma unroll
    for (int j = 0; j < 4; ++j)
#pragma unroll
      for (int r = 0; r < 4; ++r) {
        int row = quad * 4 + r;            // wave-local row
        int col = j * 16 + l15;
        int g = col >> 3, w = col & 7;
        Ps[(wave * 16 + row) * 64 + ((g ^ (row & 7)) << 3) + w] = f2b(sacc[j][r]);
      }
    __syncthreads();

#pragma unroll
    for (int ks2 = 0; ks2 < 2; ++ks2) {
      short8 ap = *(const short8*)&Ps[(wave * 16 + l15) * 64 +
                                      (((ks2 * 4 + quad) ^ (l15 & 7)) << 3)];
#pragma unroll
      for (int d = 0; d < 8; ++d) {
        int row = d * 16 + l15;
        int sl = (ks2 * 4 + quad) ^ (row & 7);
        short8 bv = *(const short8*)&Vs[row * 64 + sl * 8];
        oacc[d] = __builtin_amdgcn_mfma_f32_16x16x32_bf16(ap, bv, oacc[d], 0, 0, 0);
      }
    }
  }

  // reduce lsum across the 16 lanes (l15) that share each row
#pragma unroll
  for (int r = 0; r < 4; ++r) {
#pragma unroll
    for (int o = 1; o < 16; o <<= 1) lsum[r] += __shfl_xor(lsum[r], o, 64);
  }
#pragma unroll
  for (int r = 0; r < 4; ++r) {
    float inv = 1.0f / lsum[r];
    size_t row = (size_t)(b * S_ + q0 + wave * 16 + quad * 4 + r);
#pragma unroll
    for (int d = 0; d < 8; ++d) {
      size_t col = (size_t)h * DH_ + d * 16 + l15;
      QY[row * DM_ + col] = f2b(oacc[d][r] * inv);
    }
  }
}

// ---------------------------------------------------------------------------
extern "C" void kernel_launch(void* const* d_in, const int* in_sizes, int n_in,
                              void* d_out, int out_size, void* d_ws, size_t ws_size,
                              hipStream_t stream) {
  const float* x      = (const float*)d_in[0];
  const float* w_qkv  = (const float*)d_in[1];
  const float* w_out  = (const float*)d_in[2];
  const float* q_gain = (const float*)d_in[3];
  float* out = (float*)d_out;

  // ws (56 MiB, proven): Qraw | Kraw | Vt | wvT
  // d_out (32 MiB) doubles as scratch until the final GEMM: xbf | wqkT
  char* ws = (char*)d_ws;
  const size_t bsd = (size_t)B_ * S_ * DM_;  // 8,388,608 elems
  ushort_t* Qraw = (ushort_t*)ws;
  ushort_t* Kraw = Qraw + bsd;
  ushort_t* Vt   = Kraw + bsd;                    // [dim][b*S+s]
  ushort_t* wvT  = Vt + bsd;                      // [2048][2048]
  ushort_t* xbf  = (ushort_t*)d_out;              // [4096][2048] bf16
  ushort_t* wqkT = xbf + bsd;                     // [4096][2048] bf16 (Wq|Wk)^T
  ushort_t* woutT = Kraw;                         // after attn, Kraw is dead

  convert_f32_bf16<<<dim3(bsd / (8 * 256)), 256, 0, stream>>>(x, xbf);
  transpose_f32_to_bf16T<<<dim3(64, 32), 256, 0, stream>>>(w_qkv, wqkT, DM_, 3 * DM_, 0);
  transpose_f32_to_bf16T<<<dim3(32, 32), 256, 0, stream>>>(w_qkv, wvT, DM_, 3 * DM_, 2 * DM_);

  // Q and K in one fused GEMM (split-C epilogue)
  gemm_bt_async<2><<<dim3(32, 32), 256, 0, stream>>>(xbf, wqkT, Qraw, Kraw,
                                                     B_ * S_, 2 * DM_, DM_);
  // V^T = WvT * x^T  -> Vt[dim][b*S+s]
  gemm_bt_async<0><<<dim3(32, 16), 256, 0, stream>>>(wvT, xbf, Vt, nullptr,
                                                     DM_, B_ * S_, DM_);
  norm_rope<<<dim3(B_ * S_ * H_ / 4), 256, 0, stream>>>(Qraw, Kraw, q_gain);
  attn<<<dim3(S_ / 64, B_ * H_), 256, 0, stream>>>(Qraw, Kraw, Vt);
  // w_out^T into dead Kraw region, then final GEMM (f32 out over d_out)
  transpose_f32_to_bf16T<<<dim3(32, 32), 256, 0, stream>>>(w_out, woutT, DM_, DM_, 0);
  gemm_bt_async<1><<<dim3(16, 32), 256, 0, stream>>>(Qraw, woutT, out, nullptr,
                                                     B_ * S_, DM_, DM_);
}

// Round 6
// 442.016 us; speedup vs baseline: 1.4139x; 1.0744x over previous
//
#include <hip/hip_runtime.h>
#include <hip/hip_bf16.h>

typedef unsigned short ushort_t;
typedef __attribute__((ext_vector_type(8))) short short8;
typedef __attribute__((ext_vector_type(4))) float floatx4;

#define B_  2
#define S_  2048
#define DM_ 2048
#define H_  16
#define DH_ 128

#define AS1(p) ((const __attribute__((address_space(1))) void*)(p))
#define AS3(p) ((__attribute__((address_space(3))) void*)(p))

static __device__ __forceinline__ float b2f(ushort_t u) {
  __hip_bfloat16 h = *reinterpret_cast<__hip_bfloat16*>(&u);
  return __bfloat162float(h);
}
static __device__ __forceinline__ ushort_t f2b(float f) {
  __hip_bfloat16 h = __float2bfloat16(f);
  return *reinterpret_cast<ushort_t*>(&h);
}

// ---------------------------------------------------------------------------
// x (f32) -> bf16, 8 elems/thread.
// ---------------------------------------------------------------------------
__global__ __launch_bounds__(256) void convert_f32_bf16(const float* __restrict__ in,
                                                        ushort_t* __restrict__ out) {
  size_t i = ((size_t)blockIdx.x * 256 + threadIdx.x) * 8;
  float4 a = *(const float4*)(in + i);
  float4 b = *(const float4*)(in + i + 4);
  ushort_t tmp[8] = {f2b(a.x), f2b(a.y), f2b(a.z), f2b(a.w),
                     f2b(b.x), f2b(b.y), f2b(b.z), f2b(b.w)};
  *(uint4*)(out + i) = *(const uint4*)tmp;
}

// ---------------------------------------------------------------------------
// out[c][r] = bf16(in[r][colOff + c]); in f32 [R][inC], out bf16 [64*gx][R].
// ---------------------------------------------------------------------------
__global__ __launch_bounds__(256) void transpose_f32_to_bf16T(const float* __restrict__ in,
                                                              ushort_t* __restrict__ out,
                                                              int R, int inC, int colOff) {
  __shared__ ushort_t tile[64][72];
  const int tid = threadIdx.x;
  const int r0 = blockIdx.y * 64, c0 = blockIdx.x * 64;
#pragma unroll
  for (int p = 0; p < 2; ++p) {
    int li = tid + p * 256;
    int r = li >> 3, cs = (li & 7) * 8;
    const float* src = in + (size_t)(r0 + r) * inC + colOff + c0 + cs;
    float4 a = *(const float4*)src;
    float4 b = *(const float4*)(src + 4);
    ushort_t tmp[8] = {f2b(a.x), f2b(a.y), f2b(a.z), f2b(a.w),
                       f2b(b.x), f2b(b.y), f2b(b.z), f2b(b.w)};
    *(uint4*)&tile[r][cs] = *(const uint4*)tmp;
  }
  __syncthreads();
#pragma unroll
  for (int p = 0; p < 2; ++p) {
    int li = tid + p * 256;
    int cR = li >> 3, rs = (li & 7) * 8;
    ushort_t tmp[8];
#pragma unroll
    for (int e = 0; e < 8; ++e) tmp[e] = tile[rs + e][cR];
    *(uint4*)(out + (size_t)(c0 + cR) * R + r0 + rs) = *(const uint4*)tmp;
  }
}

// ---------------------------------------------------------------------------
// m97-style GEMM: C[M,N] = A[M,K] * Bt[N,K]^T, bf16 in, fp32 acc.
// MODE 0: C bf16, ld=N.  MODE 1: C f32, ld=N.
// MODE 2: C bf16 split: cols [0,2048) -> C0, [2048,4096) -> C1, ld=2048.
// ---------------------------------------------------------------------------
template <int MODE>
__global__ __launch_bounds__(256) void gemm_bt_async(const ushort_t* __restrict__ A,
                                                     const ushort_t* __restrict__ Bt,
                                                     void* __restrict__ C0,
                                                     void* __restrict__ C1,
                                                     int M, int N, int K) {
  __shared__ alignas(16) ushort_t As[128 * 32];
  __shared__ alignas(16) ushort_t Bs[128 * 32];
  const int tid = threadIdx.x;
  const int wave = tid >> 6, lane = tid & 63;
  const int l15 = lane & 15, quad = lane >> 4;
  const int wr = (wave >> 1) * 64, wc = (wave & 1) * 64;
  const size_t m0 = (size_t)blockIdx.y * 128, n0 = (size_t)blockIdx.x * 128;
  const int srow = lane >> 2, scol = (lane & 3) * 8;

  floatx4 zero = {0.f, 0.f, 0.f, 0.f};
  floatx4 acc[4][4];
#pragma unroll
  for (int i = 0; i < 4; ++i)
#pragma unroll
    for (int j = 0; j < 4; ++j) acc[i][j] = zero;

  for (int kt = 0; kt < K; kt += 32) {
#pragma unroll
    for (int i = 0; i < 2; ++i) {
      int c = wave * 2 + i;
      int row = c * 16 + srow;
      __builtin_amdgcn_global_load_lds(AS1(A + (m0 + row) * K + kt + scol),
                                       AS3((char*)As + c * 1024), 16, 0, 0);
      __builtin_amdgcn_global_load_lds(AS1(Bt + (n0 + row) * K + kt + scol),
                                       AS3((char*)Bs + c * 1024), 16, 0, 0);
    }
    __syncthreads();
    short8 af[4], bf[4];
#pragma unroll
    for (int i = 0; i < 4; ++i)
      af[i] = *(const short8*)&As[(wr + i * 16 + l15) * 32 + quad * 8];
#pragma unroll
    for (int j = 0; j < 4; ++j)
      bf[j] = *(const short8*)&Bs[(wc + j * 16 + l15) * 32 + quad * 8];
#pragma unroll
    for (int i = 0; i < 4; ++i)
#pragma unroll
      for (int j = 0; j < 4; ++j)
        acc[i][j] = __builtin_amdgcn_mfma_f32_16x16x32_bf16(af[i], bf[j], acc[i][j], 0, 0, 0);
    __syncthreads();
  }

  if (MODE == 2) {
    ushort_t* Cb = (n0 >= 2048) ? (ushort_t*)C1 : (ushort_t*)C0;
    size_t nc0 = n0 & 2047;
#pragma unroll
    for (int i = 0; i < 4; ++i)
#pragma unroll
      for (int j = 0; j < 4; ++j)
#pragma unroll
        for (int r = 0; r < 4; ++r) {
          size_t row = m0 + wr + i * 16 + quad * 4 + r;
          size_t col = nc0 + wc + j * 16 + l15;
          Cb[row * 2048 + col] = f2b(acc[i][j][r]);
        }
  } else {
#pragma unroll
    for (int i = 0; i < 4; ++i)
#pragma unroll
      for (int j = 0; j < 4; ++j)
#pragma unroll
        for (int r = 0; r < 4; ++r) {
          size_t row = m0 + wr + i * 16 + quad * 4 + r;
          size_t col = n0 + wc + j * 16 + l15;
          if (MODE == 1)
            ((float*)C0)[row * N + col] = acc[i][j][r];
          else
            ((ushort_t*)C0)[row * N + col] = f2b(acc[i][j][r]);
        }
  }
}

// ---------------------------------------------------------------------------
// unit-norm + RoPE (even heads) + gain-fold, in place. One wave per (b,s,h).
// ---------------------------------------------------------------------------
__global__ __launch_bounds__(256) void norm_rope(ushort_t* __restrict__ Q,
                                                 ushort_t* __restrict__ Kb,
                                                 const float* __restrict__ gain) {
  const int tid = threadIdx.x;
  const int wave = tid >> 6, lane = tid & 63;
  const int idx = blockIdx.x * 4 + wave;  // ((b*S+s)*H + h)
  const int h = idx & 15;
  const int s = (idx >> 4) & (S_ - 1);
  const size_t off = (size_t)(idx >> 4) * DM_ + h * DH_;

  float q1 = b2f(Q[off + lane]),  q2 = b2f(Q[off + 64 + lane]);
  float k1 = b2f(Kb[off + lane]), k2 = b2f(Kb[off + 64 + lane]);

  float sq = q1 * q1 + q2 * q2;
  float sk = k1 * k1 + k2 * k2;
#pragma unroll
  for (int o = 1; o < 64; o <<= 1) {
    sq += __shfl_xor(sq, o, 64);
    sk += __shfl_xor(sk, o, 64);
  }
  float rq = rsqrtf(sq + 1e-6f), rk = rsqrtf(sk + 1e-6f);
  q1 *= rq; q2 *= rq; k1 *= rk; k2 *= rk;

  float qo1 = q1, qo2 = q2, ko1 = k1, ko2 = k2;
  if ((h & 1) == 0) {  // ROPE_MASK tiles [1,0] over heads: even heads roped
    float invf = powf(10000.0f, -(float)lane * (1.0f / 64.0f));
    float th = (float)s * invf;
    float c = cosf(th), sn = sinf(th);
    qo1 = q1 * c - q2 * sn;  qo2 = q1 * sn + q2 * c;
    ko1 = k1 * c - k2 * sn;  ko2 = k1 * sn + k2 * c;
  }
  float g = gain[h];
  qo1 *= g; qo2 *= g;

  Q[off + lane]       = f2b(qo1);
  Q[off + 64 + lane]  = f2b(qo2);
  Kb[off + lane]      = f2b(ko1);
  Kb[off + 64 + lane] = f2b(ko2);
}

// ---------------------------------------------------------------------------
// Flash attention v3: balanced tile pairs {p, 31-p} (uniform 33 MFMA-tile
// iters/block), fixed-max softmax (|logit|<=12.1 by construction, M0=13, no
// running max / rescale), double-buffered K/V via global_load_lds (prefetch
// kt+1 issued after the barrier, overlapped with compute of kt), Ps is
// per-wave (no barrier needed for the C->A layout round-trip).
// LDS: 2x32 KB K/V + 16 KB Ps = 80 KB -> 2 blocks/CU. ONE barrier per iter.
// V layout: [dim][b*S+s] (row stride 4096). Y written in place over Q.
// ---------------------------------------------------------------------------
__global__ __launch_bounds__(256, 2) void attn(ushort_t* __restrict__ QY,
                                               const ushort_t* __restrict__ Kg,
                                               const ushort_t* __restrict__ Vg) {
  __shared__ alignas(16) ushort_t Ks[2][64 * 128];   // [buf][key][dim] swizzled
  __shared__ alignas(16) ushort_t Vs[2][128 * 64];   // [buf][dim][key] swizzled
  __shared__ alignas(16) ushort_t Ps[2][4][16 * 64]; // [tile][wave][row][col] swizzled

  const float M0 = 13.0f;
  const int tid = threadIdx.x;
  const int wave = tid >> 6, lane = tid & 63;
  const int l15 = lane & 15, quad = lane >> 4;
  const int bh = blockIdx.y;
  const int b = bh >> 4, h = bh & 15;
  const int p = blockIdx.x;
  const int qt[2] = {p, 31 - p};

  const ushort_t* Kgb = Kg + (size_t)b * S_ * DM_ + h * DH_;
  const ushort_t* Vgb = Vg + (size_t)(h * DH_) * (B_ * S_) + b * S_;

  // Q fragments for both tiles, straight from global
  short8 aq[2][4];
#pragma unroll
  for (int t = 0; t < 2; ++t) {
    const ushort_t* Qg =
        QY + (size_t)(b * S_ + qt[t] * 64 + wave * 16 + l15) * DM_ + h * DH_;
#pragma unroll
    for (int ks = 0; ks < 4; ++ks)
      aq[t][ks] = *(const short8*)(Qg + ks * 32 + quad * 8);
  }

  float lsum[2][4] = {{0.f, 0.f, 0.f, 0.f}, {0.f, 0.f, 0.f, 0.f}};
  floatx4 zero = {0.f, 0.f, 0.f, 0.f};
  floatx4 oacc[2][8];
#pragma unroll
  for (int t = 0; t < 2; ++t)
#pragma unroll
    for (int d = 0; d < 8; ++d) oacc[t][d] = zero;

  const int krow_in = lane >> 4, ksd = lane & 15;  // K staging: 16 lanes/row
  const int vrow_in = lane >> 3, vsd = lane & 7;   // V staging: 8 lanes/row

  // stage K/V tile kt into buffer bf
  auto stage = [&](int kt, int bf) {
#pragma unroll
    for (int i = 0; i < 4; ++i) {
      int c = wave * 4 + i;  // 0..15
      {  // K chunk: 4 rows x 128 dims
        int r = c * 4 + krow_in;
        int sg = ksd ^ (r & 7);
        __builtin_amdgcn_global_load_lds(
            AS1(Kgb + (size_t)(kt * 64 + r) * DM_ + sg * 8),
            AS3((char*)Ks[bf] + c * 1024), 16, 0, 0);
      }
      {  // V chunk: 8 rows x 64 keys
        int r = c * 8 + vrow_in;
        int sg = vsd ^ (r & 7);
        __builtin_amdgcn_global_load_lds(
            AS1(Vgb + (size_t)r * (B_ * S_) + kt * 64 + sg * 8),
            AS3((char*)Vs[bf] + c * 1024), 16, 0, 0);
      }
    }
  };

  stage(0, 0);

  for (int kt = 0; kt <= qt[1]; ++kt) {
    const int cur = kt & 1;
    __syncthreads();  // drains staging of buf[cur]; fences reuse of buf[cur^1]
    if (kt < qt[1]) stage(kt + 1, cur ^ 1);

#pragma unroll
    for (int t = 0; t < 2; ++t) {
      if (t == 0 && kt > qt[0]) continue;  // lo tile finished (uniform)
      floatx4 sacc[4];
#pragma unroll
      for (int j = 0; j < 4; ++j) sacc[j] = zero;
#pragma unroll
      for (int ks = 0; ks < 4; ++ks) {
#pragma unroll
        for (int j = 0; j < 4; ++j) {
          int row = j * 16 + l15;
          int sl = (ks * 4 + quad) ^ (row & 7);
          short8 bk = *(const short8*)&Ks[cur][row * 128 + sl * 8];
          sacc[j] = __builtin_amdgcn_mfma_f32_16x16x32_bf16(aq[t][ks], bk, sacc[j], 0, 0, 0);
        }
      }
      if (kt == qt[t]) {  // diagonal tile causal mask
#pragma unroll
        for (int j = 0; j < 4; ++j)
#pragma unroll
          for (int r = 0; r < 4; ++r) {
            int key = j * 16 + l15;
            int qr = wave * 16 + quad * 4 + r;
            if (key > qr) sacc[j][r] = -1e30f;
          }
      }
      // p = exp(s - M0); lane-local partial sums, reduced once in epilogue
#pragma unroll
      for (int j = 0; j < 4; ++j)
#pragma unroll
        for (int r = 0; r < 4; ++r) {
          float pv = __expf(sacc[j][r] - M0);
          sacc[j][r] = pv;
          lsum[t][r] += pv;
        }
      // P: C-layout -> per-wave swizzled LDS -> A-layout (wave-local, no barrier)
#pragma unroll
      for (int j = 0; j < 4; ++j)
#pragma unroll
        for (int r = 0; r < 4; ++r) {
          int row = quad * 4 + r;
          int col = j * 16 + l15;
          int g = col >> 3, w = col & 7;
          Ps[t][wave][row * 64 + ((g ^ (row & 7)) << 3) + w] = f2b(sacc[j][r]);
        }
#pragma unroll
      for (int ks2 = 0; ks2 < 2; ++ks2) {
        short8 ap = *(const short8*)&Ps[t][wave][l15 * 64 +
                                                (((ks2 * 4 + quad) ^ (l15 & 7)) << 3)];
#pragma unroll
        for (int d = 0; d < 8; ++d) {
          int row = d * 16 + l15;
          int sl = (ks2 * 4 + quad) ^ (row & 7);
          short8 bv = *(const short8*)&Vs[cur][row * 64 + sl * 8];
          oacc[t][d] = __builtin_amdgcn_mfma_f32_16x16x32_bf16(ap, bv, oacc[t][d], 0, 0, 0);
        }
      }
    }
  }

#pragma unroll
  for (int t = 0; t < 2; ++t) {
#pragma unroll
    for (int r = 0; r < 4; ++r) {
#pragma unroll
      for (int o = 1; o < 16; o <<= 1) lsum[t][r] += __shfl_xor(lsum[t][r], o, 64);
      float inv = 1.0f / lsum[t][r];
      size_t row = (size_t)(b * S_ + qt[t] * 64 + wave * 16 + quad * 4 + r);
#pragma unroll
      for (int d = 0; d < 8; ++d) {
        size_t col = (size_t)h * DH_ + d * 16 + l15;
        QY[row * DM_ + col] = f2b(oacc[t][d][r] * inv);
      }
    }
  }
}

// ---------------------------------------------------------------------------
extern "C" void kernel_launch(void* const* d_in, const int* in_sizes, int n_in,
                              void* d_out, int out_size, void* d_ws, size_t ws_size,
                              hipStream_t stream) {
  const float* x      = (const float*)d_in[0];
  const float* w_qkv  = (const float*)d_in[1];
  const float* w_out  = (const float*)d_in[2];
  const float* q_gain = (const float*)d_in[3];
  float* out = (float*)d_out;

  // ws (56 MiB, proven): Qraw | Kraw | Vt | wvT
  // d_out (32 MiB) doubles as scratch until the final GEMM: xbf | wqkT
  char* ws = (char*)d_ws;
  const size_t bsd = (size_t)B_ * S_ * DM_;  // 8,388,608 elems
  ushort_t* Qraw = (ushort_t*)ws;
  ushort_t* Kraw = Qraw + bsd;
  ushort_t* Vt   = Kraw + bsd;                    // [dim][b*S+s]
  ushort_t* wvT  = Vt + bsd;                      // [2048][2048]
  ushort_t* xbf  = (ushort_t*)d_out;              // [4096][2048] bf16
  ushort_t* wqkT = xbf + bsd;                     // [4096][2048] bf16 (Wq|Wk)^T
  ushort_t* woutT = Kraw;                         // after attn, Kraw is dead

  convert_f32_bf16<<<dim3(bsd / (8 * 256)), 256, 0, stream>>>(x, xbf);
  transpose_f32_to_bf16T<<<dim3(64, 32), 256, 0, stream>>>(w_qkv, wqkT, DM_, 3 * DM_, 0);
  transpose_f32_to_bf16T<<<dim3(32, 32), 256, 0, stream>>>(w_qkv, wvT, DM_, 3 * DM_, 2 * DM_);

  // Q and K in one fused GEMM (split-C epilogue)
  gemm_bt_async<2><<<dim3(32, 32), 256, 0, stream>>>(xbf, wqkT, Qraw, Kraw,
                                                     B_ * S_, 2 * DM_, DM_);
  // V^T = WvT * x^T  -> Vt[dim][b*S+s]
  gemm_bt_async<0><<<dim3(32, 16), 256, 0, stream>>>(wvT, xbf, Vt, nullptr,
                                                     DM_, B_ * S_, DM_);
  norm_rope<<<dim3(B_ * S_ * H_ / 4), 256, 0, stream>>>(Qraw, Kraw, q_gain);
  attn<<<dim3(S_ / 128, B_ * H_), 256, 0, stream>>>(Qraw, Kraw, Vt);
  // w_out^T into dead Kraw region, then final GEMM (f32 out over d_out)
  transpose_f32_to_bf16T<<<dim3(32, 32), 256, 0, stream>>>(w_out, woutT, DM_, DM_, 0);
  gemm_bt_async<1><<<dim3(16, 32), 256, 0, stream>>>(Qraw, woutT, out, nullptr,
                                                     B_ * S_, DM_, DM_);
}

// Round 7
// 418.629 us; speedup vs baseline: 1.4929x; 1.0559x over previous
//
#include <hip/hip_runtime.h>
#include <hip/hip_bf16.h>

typedef unsigned short ushort_t;
typedef __attribute__((ext_vector_type(8))) short short8;
typedef __attribute__((ext_vector_type(4))) float floatx4;

#define B_  2
#define S_  2048
#define DM_ 2048
#define H_  16
#define DH_ 128

#define AS1(p) ((const __attribute__((address_space(1))) void*)(p))
#define AS3(p) ((__attribute__((address_space(3))) void*)(p))

static __device__ __forceinline__ float b2f(ushort_t u) {
  __hip_bfloat16 h = *reinterpret_cast<__hip_bfloat16*>(&u);
  return __bfloat162float(h);
}
static __device__ __forceinline__ ushort_t f2b(float f) {
  __hip_bfloat16 h = __float2bfloat16(f);
  return *reinterpret_cast<ushort_t*>(&h);
}

// ---------------------------------------------------------------------------
// x (f32) -> bf16, 8 elems/thread.
// ---------------------------------------------------------------------------
__global__ __launch_bounds__(256) void convert_f32_bf16(const float* __restrict__ in,
                                                        ushort_t* __restrict__ out) {
  size_t i = ((size_t)blockIdx.x * 256 + threadIdx.x) * 8;
  float4 a = *(const float4*)(in + i);
  float4 b = *(const float4*)(in + i + 4);
  ushort_t tmp[8] = {f2b(a.x), f2b(a.y), f2b(a.z), f2b(a.w),
                     f2b(b.x), f2b(b.y), f2b(b.z), f2b(b.w)};
  *(uint4*)(out + i) = *(const uint4*)tmp;
}

// ---------------------------------------------------------------------------
// out[c][r] = bf16(in[r][colOff + c]); in f32 [R][inC], out bf16 [64*gx][R].
// ---------------------------------------------------------------------------
__global__ __launch_bounds__(256) void transpose_f32_to_bf16T(const float* __restrict__ in,
                                                              ushort_t* __restrict__ out,
                                                              int R, int inC, int colOff) {
  __shared__ ushort_t tile[64][72];
  const int tid = threadIdx.x;
  const int r0 = blockIdx.y * 64, c0 = blockIdx.x * 64;
#pragma unroll
  for (int p = 0; p < 2; ++p) {
    int li = tid + p * 256;
    int r = li >> 3, cs = (li & 7) * 8;
    const float* src = in + (size_t)(r0 + r) * inC + colOff + c0 + cs;
    float4 a = *(const float4*)src;
    float4 b = *(const float4*)(src + 4);
    ushort_t tmp[8] = {f2b(a.x), f2b(a.y), f2b(a.z), f2b(a.w),
                       f2b(b.x), f2b(b.y), f2b(b.z), f2b(b.w)};
    *(uint4*)&tile[r][cs] = *(const uint4*)tmp;
  }
  __syncthreads();
#pragma unroll
  for (int p = 0; p < 2; ++p) {
    int li = tid + p * 256;
    int cR = li >> 3, rs = (li & 7) * 8;
    ushort_t tmp[8];
#pragma unroll
    for (int e = 0; e < 8; ++e) tmp[e] = tile[rs + e][cR];
    *(uint4*)(out + (size_t)(c0 + cR) * R + r0 + rs) = *(const uint4*)tmp;
  }
}

// ---------------------------------------------------------------------------
// GEMM v2: C[M,N] = A[M,K] * Bt[N,K]^T, bf16 in, fp32 acc.
// Single-barrier double-buffered K-loop (prefetch kt+1 after the barrier,
// compute kt from the other buffer) + banded block swizzle (4-row bands,
// column-major within band) for L2 tile reuse.
// MODE 0: C bf16, ld=N.  MODE 1: C f32, ld=N.
// MODE 2: C bf16 split: cols [0,2048) -> C0, [2048,4096) -> C1, ld=2048.
// ---------------------------------------------------------------------------
template <int MODE>
__global__ __launch_bounds__(256) void gemm_bt_async(const ushort_t* __restrict__ A,
                                                     const ushort_t* __restrict__ Bt,
                                                     void* __restrict__ C0,
                                                     void* __restrict__ C1,
                                                     int M, int N, int K) {
  __shared__ alignas(16) ushort_t As[2][128 * 32];
  __shared__ alignas(16) ushort_t Bs[2][128 * 32];
  const int tid = threadIdx.x;
  const int wave = tid >> 6, lane = tid & 63;
  const int l15 = lane & 15, quad = lane >> 4;
  const int wr = (wave >> 1) * 64, wc = (wave & 1) * 64;
  // banded swizzle: gy assumed % 4 == 0
  const int lin = blockIdx.y * gridDim.x + blockIdx.x;
  const int band = lin / (4 * gridDim.x);
  const int rin = lin % (4 * gridDim.x);
  const int by = band * 4 + (rin & 3);
  const int bx = rin >> 2;
  const size_t m0 = (size_t)by * 128, n0 = (size_t)bx * 128;
  const int srow = lane >> 2, scol = (lane & 3) * 8;

  floatx4 zero = {0.f, 0.f, 0.f, 0.f};
  floatx4 acc[4][4];
#pragma unroll
  for (int i = 0; i < 4; ++i)
#pragma unroll
    for (int j = 0; j < 4; ++j) acc[i][j] = zero;

  auto stage = [&](int kt, int bf) {
#pragma unroll
    for (int i = 0; i < 2; ++i) {
      int c = wave * 2 + i;
      int row = c * 16 + srow;
      __builtin_amdgcn_global_load_lds(AS1(A + (m0 + row) * K + kt + scol),
                                       AS3((char*)As[bf] + c * 1024), 16, 0, 0);
      __builtin_amdgcn_global_load_lds(AS1(Bt + (n0 + row) * K + kt + scol),
                                       AS3((char*)Bs[bf] + c * 1024), 16, 0, 0);
    }
  };

  stage(0, 0);
  const int niter = K / 32;
  for (int it = 0; it < niter; ++it) {
    const int cur = it & 1;
    __syncthreads();  // drains staging of buf[cur]; fences reuse of buf[cur^1]
    if (it + 1 < niter) stage((it + 1) * 32, cur ^ 1);

    short8 af[4], bfr[4];
#pragma unroll
    for (int i = 0; i < 4; ++i)
      af[i] = *(const short8*)&As[cur][(wr + i * 16 + l15) * 32 + quad * 8];
#pragma unroll
    for (int j = 0; j < 4; ++j)
      bfr[j] = *(const short8*)&Bs[cur][(wc + j * 16 + l15) * 32 + quad * 8];
#pragma unroll
    for (int i = 0; i < 4; ++i)
#pragma unroll
      for (int j = 0; j < 4; ++j)
        acc[i][j] = __builtin_amdgcn_mfma_f32_16x16x32_bf16(af[i], bfr[j], acc[i][j], 0, 0, 0);
  }

  if (MODE == 2) {
    ushort_t* Cb = (n0 >= 2048) ? (ushort_t*)C1 : (ushort_t*)C0;
    size_t nc0 = n0 & 2047;
#pragma unroll
    for (int i = 0; i < 4; ++i)
#pragma unroll
      for (int j = 0; j < 4; ++j)
#pragma unroll
        for (int r = 0; r < 4; ++r) {
          size_t row = m0 + wr + i * 16 + quad * 4 + r;
          size_t col = nc0 + wc + j * 16 + l15;
          Cb[row * 2048 + col] = f2b(acc[i][j][r]);
        }
  } else {
#pragma unroll
    for (int i = 0; i < 4; ++i)
#pragma unroll
      for (int j = 0; j < 4; ++j)
#pragma unroll
        for (int r = 0; r < 4; ++r) {
          size_t row = m0 + wr + i * 16 + quad * 4 + r;
          size_t col = n0 + wc + j * 16 + l15;
          if (MODE == 1)
            ((float*)C0)[row * N + col] = acc[i][j][r];
          else
            ((ushort_t*)C0)[row * N + col] = f2b(acc[i][j][r]);
        }
  }
}

// ---------------------------------------------------------------------------
// unit-norm + RoPE (even heads) + gain-fold, in place. One wave per (b,s,h).
// ---------------------------------------------------------------------------
__global__ __launch_bounds__(256) void norm_rope(ushort_t* __restrict__ Q,
                                                 ushort_t* __restrict__ Kb,
                                                 const float* __restrict__ gain) {
  const int tid = threadIdx.x;
  const int wave = tid >> 6, lane = tid & 63;
  const int idx = blockIdx.x * 4 + wave;  // ((b*S+s)*H + h)
  const int h = idx & 15;
  const int s = (idx >> 4) & (S_ - 1);
  const size_t off = (size_t)(idx >> 4) * DM_ + h * DH_;

  float q1 = b2f(Q[off + lane]),  q2 = b2f(Q[off + 64 + lane]);
  float k1 = b2f(Kb[off + lane]), k2 = b2f(Kb[off + 64 + lane]);

  float sq = q1 * q1 + q2 * q2;
  float sk = k1 * k1 + k2 * k2;
#pragma unroll
  for (int o = 1; o < 64; o <<= 1) {
    sq += __shfl_xor(sq, o, 64);
    sk += __shfl_xor(sk, o, 64);
  }
  float rq = rsqrtf(sq + 1e-6f), rk = rsqrtf(sk + 1e-6f);
  q1 *= rq; q2 *= rq; k1 *= rk; k2 *= rk;

  float qo1 = q1, qo2 = q2, ko1 = k1, ko2 = k2;
  if ((h & 1) == 0) {  // ROPE_MASK tiles [1,0] over heads: even heads roped
    float invf = powf(10000.0f, -(float)lane * (1.0f / 64.0f));
    float th = (float)s * invf;
    float c = cosf(th), sn = sinf(th);
    qo1 = q1 * c - q2 * sn;  qo2 = q1 * sn + q2 * c;
    ko1 = k1 * c - k2 * sn;  ko2 = k1 * sn + k2 * c;
  }
  float g = gain[h];
  qo1 *= g; qo2 *= g;

  Q[off + lane]       = f2b(qo1);
  Q[off + 64 + lane]  = f2b(qo2);
  Kb[off + lane]      = f2b(ko1);
  Kb[off + 64 + lane] = f2b(ko2);
}

// ---------------------------------------------------------------------------
// Flash attention v3 (unchanged from round 6): balanced tile pairs {p, 31-p},
// fixed-max softmax (M0=13), double-buffered K/V, per-wave Ps, 1 barrier/iter.
// V layout: [dim][b*S+s]. Y written in place over Q.
// ---------------------------------------------------------------------------
__global__ __launch_bounds__(256, 2) void attn(ushort_t* __restrict__ QY,
                                               const ushort_t* __restrict__ Kg,
                                               const ushort_t* __restrict__ Vg) {
  __shared__ alignas(16) ushort_t Ks[2][64 * 128];
  __shared__ alignas(16) ushort_t Vs[2][128 * 64];
  __shared__ alignas(16) ushort_t Ps[2][4][16 * 64];

  const float M0 = 13.0f;
  const int tid = threadIdx.x;
  const int wave = tid >> 6, lane = tid & 63;
  const int l15 = lane & 15, quad = lane >> 4;
  const int bh = blockIdx.y;
  const int b = bh >> 4, h = bh & 15;
  const int p = blockIdx.x;
  const int qt[2] = {p, 31 - p};

  const ushort_t* Kgb = Kg + (size_t)b * S_ * DM_ + h * DH_;
  const ushort_t* Vgb = Vg + (size_t)(h * DH_) * (B_ * S_) + b * S_;

  short8 aq[2][4];
#pragma unroll
  for (int t = 0; t < 2; ++t) {
    const ushort_t* Qg =
        QY + (size_t)(b * S_ + qt[t] * 64 + wave * 16 + l15) * DM_ + h * DH_;
#pragma unroll
    for (int ks = 0; ks < 4; ++ks)
      aq[t][ks] = *(const short8*)(Qg + ks * 32 + quad * 8);
  }

  float lsum[2][4] = {{0.f, 0.f, 0.f, 0.f}, {0.f, 0.f, 0.f, 0.f}};
  floatx4 zero = {0.f, 0.f, 0.f, 0.f};
  floatx4 oacc[2][8];
#pragma unroll
  for (int t = 0; t < 2; ++t)
#pragma unroll
    for (int d = 0; d < 8; ++d) oacc[t][d] = zero;

  const int krow_in = lane >> 4, ksd = lane & 15;
  const int vrow_in = lane >> 3, vsd = lane & 7;

  auto stage = [&](int kt, int bf) {
#pragma unroll
    for (int i = 0; i < 4; ++i) {
      int c = wave * 4 + i;
      {
        int r = c * 4 + krow_in;
        int sg = ksd ^ (r & 7);
        __builtin_amdgcn_global_load_lds(
            AS1(Kgb + (size_t)(kt * 64 + r) * DM_ + sg * 8),
            AS3((char*)Ks[bf] + c * 1024), 16, 0, 0);
      }
      {
        int r = c * 8 + vrow_in;
        int sg = vsd ^ (r & 7);
        __builtin_amdgcn_global_load_lds(
            AS1(Vgb + (size_t)r * (B_ * S_) + kt * 64 + sg * 8),
            AS3((char*)Vs[bf] + c * 1024), 16, 0, 0);
      }
    }
  };

  stage(0, 0);

  for (int kt = 0; kt <= qt[1]; ++kt) {
    const int cur = kt & 1;
    __syncthreads();
    if (kt < qt[1]) stage(kt + 1, cur ^ 1);

#pragma unroll
    for (int t = 0; t < 2; ++t) {
      if (t == 0 && kt > qt[0]) continue;
      floatx4 sacc[4];
#pragma unroll
      for (int j = 0; j < 4; ++j) sacc[j] = zero;
#pragma unroll
      for (int ks = 0; ks < 4; ++ks) {
#pragma unroll
        for (int j = 0; j < 4; ++j) {
          int row = j * 16 + l15;
          int sl = (ks * 4 + quad) ^ (row & 7);
          short8 bk = *(const short8*)&Ks[cur][row * 128 + sl * 8];
          sacc[j] = __builtin_amdgcn_mfma_f32_16x16x32_bf16(aq[t][ks], bk, sacc[j], 0, 0, 0);
        }
      }
      if (kt == qt[t]) {
#pragma unroll
        for (int j = 0; j < 4; ++j)
#pragma unroll
          for (int r = 0; r < 4; ++r) {
            int key = j * 16 + l15;
            int qr = wave * 16 + quad * 4 + r;
            if (key > qr) sacc[j][r] = -1e30f;
          }
      }
#pragma unroll
      for (int j = 0; j < 4; ++j)
#pragma unroll
        for (int r = 0; r < 4; ++r) {
          float pv = __expf(sacc[j][r] - M0);
          sacc[j][r] = pv;
          lsum[t][r] += pv;
        }
#pragma unroll
      for (int j = 0; j < 4; ++j)
#pragma unroll
        for (int r = 0; r < 4; ++r) {
          int row = quad * 4 + r;
          int col = j * 16 + l15;
          int g = col >> 3, w = col & 7;
          Ps[t][wave][row * 64 + ((g ^ (row & 7)) << 3) + w] = f2b(sacc[j][r]);
        }
#pragma unroll
      for (int ks2 = 0; ks2 < 2; ++ks2) {
        short8 ap = *(const short8*)&Ps[t][wave][l15 * 64 +
                                                (((ks2 * 4 + quad) ^ (l15 & 7)) << 3)];
#pragma unroll
        for (int d = 0; d < 8; ++d) {
          int row = d * 16 + l15;
          int sl = (ks2 * 4 + quad) ^ (row & 7);
          short8 bv = *(const short8*)&Vs[cur][row * 64 + sl * 8];
          oacc[t][d] = __builtin_amdgcn_mfma_f32_16x16x32_bf16(ap, bv, oacc[t][d], 0, 0, 0);
        }
      }
    }
  }

#pragma unroll
  for (int t = 0; t < 2; ++t) {
#pragma unroll
    for (int r = 0; r < 4; ++r) {
#pragma unroll
      for (int o = 1; o < 16; o <<= 1) lsum[t][r] += __shfl_xor(lsum[t][r], o, 64);
      float inv = 1.0f / lsum[t][r];
      size_t row = (size_t)(b * S_ + qt[t] * 64 + wave * 16 + quad * 4 + r);
#pragma unroll
      for (int d = 0; d < 8; ++d) {
        size_t col = (size_t)h * DH_ + d * 16 + l15;
        QY[row * DM_ + col] = f2b(oacc[t][d][r] * inv);
      }
    }
  }
}

// ---------------------------------------------------------------------------
extern "C" void kernel_launch(void* const* d_in, const int* in_sizes, int n_in,
                              void* d_out, int out_size, void* d_ws, size_t ws_size,
                              hipStream_t stream) {
  const float* x      = (const float*)d_in[0];
  const float* w_qkv  = (const float*)d_in[1];
  const float* w_out  = (const float*)d_in[2];
  const float* q_gain = (const float*)d_in[3];
  float* out = (float*)d_out;

  // ws (56 MiB, proven): Qraw | Kraw | Vt | wvT
  // d_out (32 MiB) doubles as scratch until the final GEMM: xbf | wqkT
  char* ws = (char*)d_ws;
  const size_t bsd = (size_t)B_ * S_ * DM_;  // 8,388,608 elems
  ushort_t* Qraw = (ushort_t*)ws;
  ushort_t* Kraw = Qraw + bsd;
  ushort_t* Vt   = Kraw + bsd;                    // [dim][b*S+s]
  ushort_t* wvT  = Vt + bsd;                      // [2048][2048]
  ushort_t* xbf  = (ushort_t*)d_out;              // [4096][2048] bf16
  ushort_t* wqkT = xbf + bsd;                     // [4096][2048] bf16 (Wq|Wk)^T
  ushort_t* woutT = Kraw;                         // after attn, Kraw is dead

  convert_f32_bf16<<<dim3(bsd / (8 * 256)), 256, 0, stream>>>(x, xbf);
  transpose_f32_to_bf16T<<<dim3(64, 32), 256, 0, stream>>>(w_qkv, wqkT, DM_, 3 * DM_, 0);
  transpose_f32_to_bf16T<<<dim3(32, 32), 256, 0, stream>>>(w_qkv, wvT, DM_, 3 * DM_, 2 * DM_);

  // Q and K in one fused GEMM (split-C epilogue)
  gemm_bt_async<2><<<dim3(32, 32), 256, 0, stream>>>(xbf, wqkT, Qraw, Kraw,
                                                     B_ * S_, 2 * DM_, DM_);
  // V^T = WvT * x^T  -> Vt[dim][b*S+s]
  gemm_bt_async<0><<<dim3(32, 16), 256, 0, stream>>>(wvT, xbf, Vt, nullptr,
                                                     DM_, B_ * S_, DM_);
  norm_rope<<<dim3(B_ * S_ * H_ / 4), 256, 0, stream>>>(Qraw, Kraw, q_gain);
  attn<<<dim3(S_ / 128, B_ * H_), 256, 0, stream>>>(Qraw, Kraw, Vt);
  // w_out^T into dead Kraw region, then final GEMM (f32 out over d_out)
  transpose_f32_to_bf16T<<<dim3(32, 32), 256, 0, stream>>>(w_out, woutT, DM_, DM_, 0);
  gemm_bt_async<1><<<dim3(16, 32), 256, 0, stream>>>(Qraw, woutT, out, nullptr,
                                                     B_ * S_, DM_, DM_);
}